// Round 7
// baseline (2257.773 us; speedup 1.0000x reference)
//
#include <hip/hip_runtime.h>
#include <math.h>

#define LDIM 384
#define NPIX (LDIM*LDIM)
#define NBINS 63

typedef __attribute__((ext_vector_type(8))) __bf16 bf16x8;
typedef __attribute__((ext_vector_type(4))) float floatx4;

__device__ __forceinline__ float sigf(float x){ return 1.f/(1.f+expf(-x)); }

// Prepped weight fragment layout (bf16): [tap][kc][nt][lane(64)][j(8)]
//   B-frag: n = nt*16 + (lane&15), k = kc*32 + (lane>>4)*8 + j
// WF arena offsets (bf16 units):
//   main conv slot s (0..11): s=2i conv1[i], s=2i+1 conv2[i], at s*36864
//   dist: 442368 ; cf1: 479232 ; cf2: 497664 ;
//   wg: 506880 (4096) ; wo: 510976 (2048) ; wq: 513024 (2048) ; total 515072
__global__ __launch_bounds__(256) void prep_kernel(
    const float* __restrict__ c1w, const float* __restrict__ c2w,
    const float* __restrict__ dw, const float* __restrict__ cf1w,
    const float* __restrict__ cf2w, const float* __restrict__ wg,
    const float* __restrict__ wo, const float* __restrict__ wq,
    __bf16* __restrict__ Wf){
  int idx = blockIdx.x*256 + threadIdx.x;
  if (idx >= 515072) return;
  if (idx >= 506880){
    int rel, NT, NDIM; const float* src;
    if (idx < 510976){ rel = idx - 506880; src = wg; NT=4; NDIM=64; }
    else if (idx < 513024){ rel = idx - 510976; src = wo; NT=4; NDIM=64; }
    else { rel = idx - 513024; src = wq; NT=2; NDIM=32; }
    int j = rel & 7, lane = (rel>>3) & 63;
    int r2 = rel >> 9;
    int nt = r2 % NT, kc = r2 / NT;
    int k = kc*32 + (lane>>4)*8 + j;
    int n = nt*16 + (lane&15);
    Wf[idx] = (__bf16)src[(size_t)k*NDIM + n];
    return;
  }
  const float* src; int ICreal, OCreal, ICP, NT, rel;
  if (idx < 442368){
    int layer = idx / 36864; rel = idx - layer*36864;
    int i = layer >> 1;
    src = (layer & 1) ? (c2w + (size_t)i*36864) : (c1w + (size_t)i*36864);
    ICreal=64; OCreal=64; ICP=64; NT=4;
  } else if (idx < 479232){
    rel = idx - 442368; src = dw;   ICreal=64; OCreal=63; ICP=64; NT=4;
  } else if (idx < 497664){
    rel = idx - 479232; src = cf1w; ICreal=63; OCreal=32; ICP=64; NT=2;
  } else {
    rel = idx - 497664; src = cf2w; ICreal=32; OCreal=32; ICP=32; NT=2;
  }
  int j = rel & 7, lane = (rel>>3) & 63;
  int r2 = rel >> 9;
  int nt = r2 % NT; int r3 = r2 / NT;
  int KC = ICP/32;
  int kc = r3 % KC; int tap = r3 / KC;
  int k = kc*32 + (lane>>4)*8 + j;
  int n = nt*16 + (lane&15);
  float v = 0.f;
  if (k < ICreal && n < OCreal) v = src[((size_t)n*ICreal + k)*9 + tap];
  Wf[idx] = (__bf16)v;
}

// ---------- MFMA implicit-GEMM 3x3 dilated conv, compile-time D ----------
template<int ICP, int NT, int D, int WAVES, bool NORM>
__global__ __launch_bounds__(WAVES*64) void mfma_conv(
    const __bf16* __restrict__ Ain, const __bf16* __restrict__ Wf,
    const float* __restrict__ bias, int OC_real,
    float* __restrict__ outF, __bf16* __restrict__ outP,
    int relu, const float* __restrict__ nstats, float* __restrict__ ostats){
  constexpr int KC = ICP/32;
  constexpr int W = WAVES*16;
  constexpr int T = WAVES*64;
  constexpr int SW = W + 2*D;
  constexpr int REC_B = ICP*4;
  constexpr int P_B = REC_B + 16;
  constexpr int PPX = ICP/8;
  constexpr int ROWP = SW*PPX;
  constexpr int TOTP = 3*ROWP;
  constexpr int NCH = (TOTP + T - 1)/T;
  constexpr int OCS = NT*16;
  const int t = threadIdx.x;
  const int wave = t>>6, lane = t&63;
  const int q = lane>>4, col16 = lane&15;
  const int y = blockIdx.y;
  const int x0 = blockIdx.x*W;
  extern __shared__ __align__(16) char smem[];
  char* stage = smem;
  float* muS = (float*)(smem + 3*SW*P_B);

  uint4 vh[NCH], vl[NCH];
  #pragma unroll
  for (int k=0;k<NCH;k++){
    uint4 z = {0u,0u,0u,0u}; vh[k]=z; vl[k]=z;
    int pp = t + k*T;
    if (pp < TOTP){
      int r = pp/ROWP; int rem = pp - r*ROWP;
      int px = rem/PPX; int sub = rem - px*PPX;
      int yr = y + (r-1)*D; int gx = x0 - D + px;
      if ((unsigned)yr < LDIM && (unsigned)gx < LDIM){
        const char* p = (const char*)Ain + ((size_t)yr*LDIM + gx)*REC_B + sub*16;
        vh[k] = *(const uint4*)p;
        vl[k] = *(const uint4*)(p + ICP*2);
      }
    }
  }

  if (NORM){
    if (t < 64){
      float s=0.f, sq=0.f;
      #pragma unroll
      for (int rp=0;rp<8;rp++){ s += nstats[rp*128 + t]; sq += nstats[rp*128 + 64 + t]; }
      float m = s*(1.f/NPIX);
      muS[t] = m;
      muS[64+t] = rsqrtf(sq*(1.f/NPIX) - m*m + 1e-5f);
    }
    __syncthreads();
    #pragma unroll
    for (int k=0;k<NCH;k++){
      int pp = t + k*T;
      if (pp < TOTP){
        int r = pp/ROWP; int rem = pp - r*ROWP;
        int px = rem/PPX; int sub = rem - px*PPX;
        int yr = y + (r-1)*D; int gx = x0 - D + px;
        if ((unsigned)yr < LDIM && (unsigned)gx < LDIM){
          int c0 = sub*8;
          floatx4 mua = *(floatx4*)(muS + c0), mub = *(floatx4*)(muS + c0 + 4);
          floatx4 rsa = *(floatx4*)(muS + 64 + c0), rsb = *(floatx4*)(muS + 64 + c0 + 4);
          __bf16* hp = (__bf16*)&vh[k]; __bf16* lp = (__bf16*)&vl[k];
          #pragma unroll
          for (int j=0;j<8;j++){
            float mu = (j<4) ? mua[j] : mub[j-4];
            float rs = (j<4) ? rsa[j] : rsb[j-4];
            float v = ((float)hp[j] + (float)lp[j] - mu)*rs;
            v = v>0.f ? v : expm1f(v);
            __bf16 h = (__bf16)v; hp[j]=h; lp[j]=(__bf16)(v-(float)h);
          }
        }
      }
    }
  }

  #pragma unroll
  for (int k=0;k<NCH;k++){
    int pp = t + k*T;
    if (pp < TOTP){
      int r = pp/ROWP; int rem = pp - r*ROWP;
      int px = rem/PPX; int sub = rem - px*PPX;
      char* sp = stage + ((size_t)r*SW + px)*P_B + sub*16;
      *(uint4*)sp = vh[k];
      *(uint4*)(sp + ICP*2) = vl[k];
    }
  }
  __syncthreads();

  floatx4 acc[NT];
  #pragma unroll
  for (int b=0;b<NT;b++){ floatx4 z = {0.f,0.f,0.f,0.f}; acc[b]=z; }

  #pragma unroll
  for (int ky=0; ky<3; ky++){
    const char* slot = stage + (size_t)ky*SW*P_B;
    #pragma unroll
    for (int kx=0; kx<3; kx++){
      #pragma unroll
      for (int kc=0; kc<KC; kc++){
        int cl = wave*16 + col16 + kx*D;
        const char* ap = slot + (size_t)cl*P_B + (kc*4+q)*16;
        bf16x8 ah = *(const bf16x8*)ap;
        bf16x8 al = *(const bf16x8*)(ap + ICP*2);
        const __bf16* wkc = Wf + (size_t)((ky*3+kx)*KC + kc)*NT*512 + lane*8;
        #pragma unroll
        for (int nt=0; nt<NT; nt++){
          bf16x8 bfrag = *(const bf16x8*)(wkc + (size_t)nt*512);
          acc[nt] = __builtin_amdgcn_mfma_f32_16x16x32_bf16(ah, bfrag, acc[nt], 0,0,0);
          acc[nt] = __builtin_amdgcn_mfma_f32_16x16x32_bf16(al, bfrag, acc[nt], 0,0,0);
        }
      }
    }
  }

  float* red = (float*)stage;
  if (ostats) __syncthreads();
  #pragma unroll
  for (int nt=0; nt<NT; nt++){
    int oc = nt*16 + col16;
    float bv = (oc < OC_real) ? bias[oc] : 0.f;
    int pxb = x0 + wave*16 + q*4;
    float s=0.f, sq=0.f;
    #pragma unroll
    for (int r=0; r<4; r++){
      float vv = acc[nt][r] + bv;
      if (relu) vv = fmaxf(vv, 0.f);
      size_t pix = (size_t)y*LDIM + pxb + r;
      if (outF) outF[pix*OCS + oc] = vv;
      if (outP){
        __bf16 h = (__bf16)vv;
        __bf16* rec = outP + pix*(size_t)(OCS*2);
        rec[oc] = h; rec[OCS+oc] = (__bf16)(vv - (float)h);
      }
      s += vv; sq += vv*vv;
    }
    if (ostats){
      s  += __shfl_xor(s, 16);  s  += __shfl_xor(s, 32);
      sq += __shfl_xor(sq, 16); sq += __shfl_xor(sq, 32);
      if (q == 0){
        red[oc*WAVES + wave] = s;
        red[OCS*WAVES + oc*WAVES + wave] = sq;
      }
    }
  }
  if (ostats){
    __syncthreads();
    float* oslot = ostats + ((blockIdx.y & 7) << 7);
    if (t < OCS){
      float s=0.f, sq=0.f;
      #pragma unroll
      for (int w=0; w<WAVES; w++){
        s  += red[t*WAVES + w];
        sq += red[OCS*WAVES + t*WAVES + w];
      }
      atomicAdd(&oslot[t], s);
      atomicAdd(&oslot[64+t], sq);
    }
  }
}

// ---------------- input 1x1 conv: NHWC(41) -> hi/lo records(64) ----------------
__global__ __launch_bounds__(256) void in_proj_kernel(
    const float* __restrict__ feat, const float* __restrict__ w,
    const float* __restrict__ b, __bf16* __restrict__ PX){
  __shared__ float sf[16][41];
  __shared__ float sw[64*41];
  int t = threadIdx.x;
  size_t p0 = (size_t)blockIdx.x*16;
  float wv[11];
  #pragma unroll
  for (int k=0;k<11;k++){ int idx=t+k*256; wv[k] = (idx<2624) ? w[idx] : 0.f; }
  float fv[3];
  #pragma unroll
  for (int k=0;k<3;k++){ int idx=t+k*256; fv[k] = (idx<656) ? feat[p0*41 + idx] : 0.f; }
  #pragma unroll
  for (int k=0;k<11;k++){ int idx=t+k*256; if (idx<2624) sw[idx]=wv[k]; }
  #pragma unroll
  for (int k=0;k<3;k++){
    int idx=t+k*256;
    if (idx<656){ int p = idx/41, k2 = idx - p*41; sf[p][k2]=fv[k]; }
  }
  __syncthreads();
  #pragma unroll
  for (int k=0;k<4;k++){
    int item = t + k*256;
    int c = item&63, p = item>>6;
    float acc = b[c];
    #pragma unroll
    for (int kk=0;kk<41;kk++) acc += sf[p][kk]*sw[c*41+kk];
    __bf16 h = (__bf16)acc;
    __bf16* rec = PX + (p0+p)*128;
    rec[c] = h; rec[64+c] = (__bf16)(acc - (float)h);
  }
}

// norm(conv2raw U, 8-replica stats) + residual(PX) -> ELU -> PX (records)
__global__ __launch_bounds__(256) void norm_res_elu_planes(
    const __bf16* __restrict__ U, __bf16* __restrict__ PX,
    const float* __restrict__ stats){
  size_t idx = (size_t)blockIdx.x*256 + threadIdx.x;
  size_t px = idx>>3; int c0 = (int)(idx&7)*8;
  const __bf16* ur = U + px*128;
  __bf16* xr = PX + px*128;
  uint4 uh = *(const uint4*)(ur + c0);
  uint4 ul = *(const uint4*)(ur + 64 + c0);
  uint4 xh = *(uint4*)(xr + c0);
  uint4 xl = *(uint4*)(xr + 64 + c0);
  __bf16* uhp=(__bf16*)&uh; __bf16* ulp=(__bf16*)&ul;
  __bf16* xhp=(__bf16*)&xh; __bf16* xlp=(__bf16*)&xl;
  float mu[8], rs[8];
  #pragma unroll
  for (int k=0;k<8;k++){
    int c = c0+k;
    float s=0.f, sq=0.f;
    #pragma unroll
    for (int rp=0;rp<8;rp++){ s += stats[rp*128 + c]; sq += stats[rp*128 + 64 + c]; }
    float m = s*(1.f/NPIX);
    mu[k]=m; rs[k]=rsqrtf(sq*(1.f/NPIX) - m*m + 1e-5f);
  }
  #pragma unroll
  for (int k=0;k<8;k++){
    float v = ((float)uhp[k] + (float)ulp[k] - mu[k])*rs[k]
            + ((float)xhp[k] + (float)xlp[k]);
    v = v>0.f ? v : expm1f(v);
    __bf16 h = (__bf16)v; xhp[k]=h; xlp[k]=(__bf16)(v-(float)h);
  }
  *(uint4*)(xr + c0) = xh;
  *(uint4*)(xr + 64 + c0) = xl;
}

// ---------------- attention ----------------
__global__ __launch_bounds__(256) void g_partial_kernel(
    const float* __restrict__ td, float* __restrict__ GC){
  size_t base = (size_t)blockIdx.x*256;
  float cnt = (td[base + threadIdx.x] > 0.f) ? 1.f : 0.f;
  __shared__ float red[256];
  red[threadIdx.x]=cnt; __syncthreads();
  for (int st=128; st; st>>=1){
    if (threadIdx.x<st) red[threadIdx.x]+=red[threadIdx.x+st];
    __syncthreads();
  }
  if (threadIdx.x==0) atomicAdd(GC, red[0]);
}

__global__ void g_final_kernel(
    const float* __restrict__ GC, const float* __restrict__ tq,
    const float* __restrict__ w1, const float* __restrict__ b1,
    const float* __restrict__ w2, const float* __restrict__ b2,
    float* __restrict__ G){
  if (threadIdx.x==0){
    float f0 = GC[0]*(1.f/NPIX), f1 = tq[0], f2 = (float)LDIM/512.f;
    float z = b2[0];
    for (int j=0;j<16;j++){
      float h = f0*w1[j] + f1*w1[16+j] + f2*w1[32+j] + b1[j];
      z += (h>0.f?h:0.f)*w2[j];
    }
    G[0] = sigf(z);
  }
}

__global__ __launch_bounds__(256) void qproj_mfma_kernel(
    const __bf16* __restrict__ PX, const __bf16* __restrict__ WqF,
    float* __restrict__ Q){
  const int t=threadIdx.x, wave=t>>6, lane=t&63, q=lane>>4, col16=lane&15;
  const size_t p0=(size_t)blockIdx.x*128;
  __shared__ __bf16 Xhi[128*72];
  __shared__ __bf16 Xlo[128*72];
  uint4 sv[8];
  #pragma unroll
  for (int k=0;k<8;k++){
    int c=t+k*256;
    sv[k] = *(const uint4*)((const char*)PX + (p0 + (c>>4))*256 + (c&15)*16);
  }
  #pragma unroll
  for (int k=0;k<8;k++){
    int c=t+k*256; int px=c>>4, sub=c&15;
    *(uint4*)(((sub<8)?Xhi:Xlo) + px*72 + (sub&7)*8) = sv[k];
  }
  __syncthreads();
  floatx4 acc[2][2];
  #pragma unroll
  for (int a=0;a<2;a++)
    #pragma unroll
    for (int b=0;b<2;b++){ floatx4 z={0.f,0.f,0.f,0.f}; acc[a][b]=z; }
  #pragma unroll
  for (int kc=0;kc<2;kc++){
    bf16x8 ah[2], al[2];
    #pragma unroll
    for (int mt=0;mt<2;mt++){
      int row = wave*32 + mt*16 + col16;
      ah[mt] = *(const bf16x8*)(Xhi + row*72 + kc*32 + q*8);
      al[mt] = *(const bf16x8*)(Xlo + row*72 + kc*32 + q*8);
    }
    #pragma unroll
    for (int nt=0;nt<2;nt++){
      bf16x8 b = *(const bf16x8*)(WqF + (kc*2+nt)*512 + lane*8);
      acc[0][nt] = __builtin_amdgcn_mfma_f32_16x16x32_bf16(ah[0], b, acc[0][nt], 0,0,0);
      acc[1][nt] = __builtin_amdgcn_mfma_f32_16x16x32_bf16(ah[1], b, acc[1][nt], 0,0,0);
      acc[0][nt] = __builtin_amdgcn_mfma_f32_16x16x32_bf16(al[0], b, acc[0][nt], 0,0,0);
      acc[1][nt] = __builtin_amdgcn_mfma_f32_16x16x32_bf16(al[1], b, acc[1][nt], 0,0,0);
    }
  }
  #pragma unroll
  for (int mt=0;mt<2;mt++){
    size_t pxb = p0 + wave*32 + mt*16 + q*4;
    #pragma unroll
    for (int nt=0;nt<2;nt++){
      int oc = nt*16 + col16;
      #pragma unroll
      for (int r=0;r<4;r++)
        Q[(pxb+r)*32 + oc] = acc[mt][nt][r];
    }
  }
}

__global__ __launch_bounds__(256) void proj_left_kernel(
    const __bf16* __restrict__ PX, const float* __restrict__ wl, const float* __restrict__ wvl,
    float* __restrict__ left, float* __restrict__ vleft){
  int i = blockIdx.x;
  __shared__ float xa[32][65];
  __shared__ float w1s[2048], w2s[2048];
  int c = threadIdx.x & 63;
  for (int a = threadIdx.x>>6; a<32; a+=4){
    const __bf16* rec = PX + ((size_t)i*LDIM + 12*a)*128;
    xa[a][c] = (float)rec[c] + (float)rec[64+c];
  }
  for (int idx=threadIdx.x; idx<2048; idx+=256){ w1s[idx]=wl[idx]; w2s[idx]=wvl[idx]; }
  __syncthreads();
  #pragma unroll
  for (int k=0;k<4;k++){
    int idx = threadIdx.x + k*256;
    int a = idx>>5, n = idx&31;
    float a1=0.f, a2=0.f;
    #pragma unroll
    for (int cc=0;cc<64;cc++){ float v=xa[a][cc]; a1+=v*w1s[cc*32+n]; a2+=v*w2s[cc*32+n]; }
    left [((size_t)i*32+a)*32+n]=a1;
    vleft[((size_t)i*32+a)*32+n]=a2;
  }
}

// grid (12, 32): j0 = bx*32, a = by
__global__ __launch_bounds__(256) void proj_right_kernel(
    const __bf16* __restrict__ PX, const float* __restrict__ wr, const float* __restrict__ wvr,
    float* __restrict__ right, float* __restrict__ vright){
  int a = blockIdx.y; int row = 12*a;
  int j0 = blockIdx.x*32;
  __shared__ float xr[32][65];
  __shared__ float w1s[2048], w2s[2048];
  for (int idx=threadIdx.x; idx<2048; idx+=256){ w1s[idx]=wr[idx]; w2s[idx]=wvr[idx]; }
  int c = threadIdx.x & 63;
  for (int jl = threadIdx.x>>6; jl<32; jl+=4){
    const __bf16* rec = PX + ((size_t)row*LDIM + j0 + jl)*128;
    xr[jl][c] = (float)rec[c] + (float)rec[64+c];
  }
  __syncthreads();
  #pragma unroll
  for (int k=0;k<4;k++){
    int idx=threadIdx.x+k*256; int jl=idx>>5, n=idx&31;
    float a1=0.f, a2=0.f;
    #pragma unroll
    for (int cc=0;cc<64;cc++){ float v=xr[jl][cc]; a1+=v*w1s[cc*32+n]; a2+=v*w2s[cc*32+n]; }
    right [((size_t)(j0+jl)*32 + a)*32 + n]=a1;
    vright[((size_t)(j0+jl)*32 + a)*32 + n]=a2;
  }
}

// scores + bias + softmax -> attn. float4 prefetch pipeline on right[j].
__global__ __launch_bounds__(128) void scores_kernel(
    const float* __restrict__ q, const float* __restrict__ left,
    const float* __restrict__ right, const float* __restrict__ td,
    const float* __restrict__ gp, float* __restrict__ attn){
  int i = blockIdx.y;
  int j0 = blockIdx.x*128;
  int j = j0 + threadIdx.x;
  __shared__ float lf[1024];
  __shared__ float tl[32];
  __shared__ float trS[32*128];
  {
    int t = threadIdx.x;
    // lf: 1024 floats = 256 f4, 128 threads x 2
    #pragma unroll
    for (int v=0; v<2; v++){
      int f = t + v*128;
      *(floatx4*)(lf + f*4) = *(const floatx4*)(left + (size_t)i*1024 + f*4);
    }
    // trS[a][jl] : td[12a][j0+jl] ; 4096 floats = 1024 f4, 8 per thread
    #pragma unroll
    for (int v=0; v<8; v++){
      int f = t + v*128;
      int a = f>>5, jl4 = (f&31)*4;
      *(floatx4*)(trS + a*128 + jl4) = *(const floatx4*)(td + (size_t)(12*a)*LDIM + j0 + jl4);
    }
    if (t<32) tl[t] = td[(size_t)i*LDIM + 12*t];
  }
  __syncthreads();
  float g = gp[0];
  floatx4 qv[8];
  const floatx4* qp4 = (const floatx4*)(q + ((size_t)i*LDIM+j)*32);
  #pragma unroll
  for (int v=0;v<8;v++) qv[v]=qp4[v];
  float tdij = td[(size_t)i*LDIM+j];
  const floatx4* rp4 = (const floatx4*)(right + (size_t)j*1024);
  floatx4 cur[8], nxt[8];
  #pragma unroll
  for (int v=0;v<8;v++) cur[v]=rp4[v];
  float s[32];
  float m = -1e30f;
  #pragma unroll
  for (int a=0;a<32;a++){
    if (a<31){
      #pragma unroll
      for (int v=0;v<8;v++) nxt[v]=rp4[(a+1)*8+v];
    }
    float acc=0.f;
    #pragma unroll
    for (int v=0;v<8;v++){
      #pragma unroll
      for (int e=0;e<4;e++)
        acc += qv[v][e]*(lf[a*32+v*4+e] + cur[v][e]);
    }
    acc *= 0.17677669529663687f;
    float bias = -fabsf(tl[a] + trS[a*128 + threadIdx.x] - tdij) * (1.0f/12.0f);
    acc += g*bias;
    s[a]=acc;
    m = fmaxf(m, acc);
    #pragma unroll
    for (int v=0;v<8;v++) cur[v]=nxt[v];
  }
  float sum=0.f;
  #pragma unroll
  for (int a=0;a<32;a++){ s[a]=expf(s[a]-m); sum+=s[a]; }
  float inv = 1.f/sum;
  floatx4* op = (floatx4*)(attn + ((size_t)i*LDIM+j)*32);
  #pragma unroll
  for (int v=0;v<8;v++){
    floatx4 o;
    #pragma unroll
    for (int e=0;e<4;e++) o[e] = s[v*4+e]*inv;
    op[v] = o;
  }
}

// upd = attn@vleft + attn@vright ; float4 prefetch on vright.
// grid (12, 384): j0 = bx*32 ; threads 256 = 32 j x 8 n-chunks
__global__ __launch_bounds__(256) void update_kernel(
    const float* __restrict__ attn, const float* __restrict__ vleft,
    const float* __restrict__ vright, float* __restrict__ upd){
  int i = blockIdx.y;
  int j0 = blockIdx.x*32;
  int t = threadIdx.x;
  int p = t>>3, ng = t&7;
  __shared__ float vl[1024];
  __shared__ float at[32][33];
  *(floatx4*)(vl + t*4) = *(const floatx4*)(vleft + (size_t)i*1024 + t*4);
  {
    floatx4 a4 = *(const floatx4*)(attn + ((size_t)i*LDIM + j0 + p)*32 + ng*4);
    #pragma unroll
    for (int e=0;e<4;e++) at[p][ng*4+e] = a4[e];
  }
  __syncthreads();
  const floatx4* vr4 = (const floatx4*)(vright + (size_t)(j0+p)*1024) + ng;
  floatx4 c0 = vr4[0], c1 = vr4[8];
  floatx4 acc = {0.f,0.f,0.f,0.f};
  #pragma unroll
  for (int a=0;a<32;a++){
    floatx4 nx = c1;
    if (a<30) nx = vr4[(size_t)(a+2)*8];
    float w = at[p][a];
    floatx4 vl4 = *(const floatx4*)(vl + a*32 + ng*4);
    #pragma unroll
    for (int e=0;e<4;e++) acc[e] += w*(vl4[e] + c0[e]);
    c0 = c1; c1 = nx;
  }
  *(floatx4*)(upd + ((size_t)i*LDIM + j0+p)*32 + ng*4) = acc;
}

// PX += sigmoid(X@Wg+bg) * (UPD@Wo), in-place on records, via MFMA
__global__ __launch_bounds__(256) void gate_mfma_kernel(
    __bf16* __restrict__ PX, const float* __restrict__ UPD,
    const __bf16* __restrict__ WgF, const __bf16* __restrict__ WoF,
    const float* __restrict__ bg){
  const int t=threadIdx.x, wave=t>>6, lane=t&63, q=lane>>4, col16=lane&15;
  const size_t p0=(size_t)blockIdx.x*128;
  __shared__ __bf16 Xhi[128*72];
  __shared__ __bf16 Xlo[128*72];
  __shared__ __bf16 Ub[128*40];
  uint4 sv[8];
  #pragma unroll
  for (int k=0;k<8;k++){
    int c=t+k*256;
    sv[k] = *(const uint4*)((const char*)PX + (p0 + (c>>4))*256 + (c&15)*16);
  }
  floatx4 uv[4];
  #pragma unroll
  for (int k=0;k<4;k++){
    int p = (t>>3) + k*32;
    uv[k] = *(const floatx4*)(UPD + (p0+p)*32 + (t&7)*4);
  }
  #pragma unroll
  for (int k=0;k<8;k++){
    int c=t+k*256; int px=c>>4, sub=c&15;
    *(uint4*)(((sub<8)?Xhi:Xlo) + px*72 + (sub&7)*8) = sv[k];
  }
  #pragma unroll
  for (int k=0;k<4;k++){
    int p = (t>>3) + k*32;
    __bf16* pu = Ub + p*40 + (t&7)*4;
    #pragma unroll
    for (int kk=0;kk<4;kk++) pu[kk]=(__bf16)uv[k][kk];
  }
  __syncthreads();
  floatx4 accg[2][4], accu[2][4];
  #pragma unroll
  for (int a=0;a<2;a++)
    #pragma unroll
    for (int b=0;b<4;b++){ floatx4 z={0.f,0.f,0.f,0.f}; accg[a][b]=z; accu[a][b]=z; }
  #pragma unroll
  for (int kc=0;kc<2;kc++){
    bf16x8 ah[2], al[2];
    #pragma unroll
    for (int mt=0;mt<2;mt++){
      int row = wave*32 + mt*16 + col16;
      ah[mt] = *(const bf16x8*)(Xhi + row*72 + kc*32 + q*8);
      al[mt] = *(const bf16x8*)(Xlo + row*72 + kc*32 + q*8);
    }
    #pragma unroll
    for (int nt=0;nt<4;nt++){
      bf16x8 b = *(const bf16x8*)(WgF + (kc*4+nt)*512 + lane*8);
      accg[0][nt] = __builtin_amdgcn_mfma_f32_16x16x32_bf16(ah[0], b, accg[0][nt], 0,0,0);
      accg[1][nt] = __builtin_amdgcn_mfma_f32_16x16x32_bf16(ah[1], b, accg[1][nt], 0,0,0);
      accg[0][nt] = __builtin_amdgcn_mfma_f32_16x16x32_bf16(al[0], b, accg[0][nt], 0,0,0);
      accg[1][nt] = __builtin_amdgcn_mfma_f32_16x16x32_bf16(al[1], b, accg[1][nt], 0,0,0);
    }
  }
  {
    bf16x8 au[2];
    #pragma unroll
    for (int mt=0;mt<2;mt++){
      int row = wave*32 + mt*16 + col16;
      au[mt] = *(const bf16x8*)(Ub + row*40 + q*8);
    }
    #pragma unroll
    for (int nt=0;nt<4;nt++){
      bf16x8 b = *(const bf16x8*)(WoF + nt*512 + lane*8);
      accu[0][nt] = __builtin_amdgcn_mfma_f32_16x16x32_bf16(au[0], b, accu[0][nt], 0,0,0);
      accu[1][nt] = __builtin_amdgcn_mfma_f32_16x16x32_bf16(au[1], b, accu[1][nt], 0,0,0);
    }
  }
  #pragma unroll
  for (int mt=0;mt<2;mt++){
    size_t pxb = p0 + wave*32 + mt*16 + q*4;
    #pragma unroll
    for (int nt=0;nt<4;nt++){
      int oc = nt*16 + col16;
      float bgv = bg[oc];
      #pragma unroll
      for (int r=0;r<4;r++){
        __bf16* rec = PX + (pxb+r)*128;
        float xv = (float)rec[oc] + (float)rec[64+oc];
        float g = sigf(accg[mt][nt][r] + bgv);
        float xn = xv + g*accu[mt][nt][r];
        __bf16 h = (__bf16)xn;
        rec[oc] = h; rec[64+oc] = (__bf16)(xn - (float)h);
      }
    }
  }
}

// ---------------- heads ----------------
__global__ __launch_bounds__(256) void sym_kernel(
    const float* __restrict__ lg, __bf16* __restrict__ PS, float* __restrict__ dout){
  int i = blockIdx.y;
  int j = blockIdx.x*4 + (threadIdx.x>>6);
  int o = threadIdx.x & 63;
  float v = 0.5f*(lg[((size_t)i*LDIM+j)*64+o] + lg[((size_t)j*LDIM+i)*64+o]);
  size_t pix = (size_t)i*LDIM+j;
  __bf16 h = (__bf16)v;
  __bf16* rec = PS + pix*128;
  rec[o] = h; rec[64+o] = (__bf16)(v - (float)h);
  if (o<63) dout[pix*63+o] = v;
}

__global__ __launch_bounds__(256) void conf_kernel(
    const float* __restrict__ c2, const float* __restrict__ w,
    const float* __restrict__ b, float* __restrict__ out){
  int t = threadIdx.x;
  size_t pix = (size_t)blockIdx.x*8 + (t>>5);
  int c = t&31;
  float v = c2[pix*32 + c]*w[c];
  #pragma unroll
  for (int off=16; off; off>>=1) v += __shfl_xor(v, off);
  if (c==0) out[pix] = sigf(v + b[0]);
}

extern "C" void kernel_launch(void* const* d_in, const int* in_sizes, int n_in,
                              void* d_out, int out_size, void* d_ws, size_t ws_size,
                              hipStream_t stream){
  const float* feat = (const float*)d_in[0];
  const float* td   = (const float*)d_in[1];
  const float* tq   = (const float*)d_in[2];
  const float* in_w = (const float*)d_in[3];
  const float* in_b = (const float*)d_in[4];
  const float* c1w  = (const float*)d_in[5];
  const float* c1b  = (const float*)d_in[6];
  const float* c2w  = (const float*)d_in[7];
  const float* c2b  = (const float*)d_in[8];
  const float* wq   = (const float*)d_in[9];
  const float* wl   = (const float*)d_in[10];
  const float* wr   = (const float*)d_in[11];
  const float* wvl  = (const float*)d_in[12];
  const float* wvr  = (const float*)d_in[13];
  const float* wo   = (const float*)d_in[14];
  const float* wg   = (const float*)d_in[15];
  const float* bg   = (const float*)d_in[16];
  const float* tgw1 = (const float*)d_in[17];
  const float* tgb1 = (const float*)d_in[18];
  const float* tgw2 = (const float*)d_in[19];
  const float* tgb2 = (const float*)d_in[20];
  const float* dw   = (const float*)d_in[21];
  const float* db   = (const float*)d_in[22];
  const float* cf1w = (const float*)d_in[23];
  const float* cf1b = (const float*)d_in[24];
  const float* cf2w = (const float*)d_in[25];
  const float* cf2b = (const float*)d_in[26];
  const float* cf3w = (const float*)d_in[27];
  const float* cf3b = (const float*)d_in[28];

  float* ws = (float*)d_ws;
  const size_t BUF = (size_t)64*NPIX;
  float* R1 = ws;
  float* R2 = ws + BUF;
  float* R3 = ws + 2*BUF;
  float* STATS = ws + 3*BUF;             // 12 slots x 8 replicas x 128
  float* G     = STATS + 12288;
  float* GC    = G + 1;
  __bf16* WF   = (__bf16*)(G + 16);
  __bf16* WGF  = WF + 506880;
  __bf16* WOF  = WF + 510976;
  __bf16* WQF  = WF + 513024;

  __bf16* PX = (__bf16*)R1;
  __bf16* PT = (__bf16*)R2;
  __bf16* PU = (__bf16*)R3;
  float* Q      = R2;
  float* LEFTB  = R2 + (size_t)32*NPIX;
  float* RIGHTB = LEFTB + 393216;
  float* VLEFT  = RIGHTB + 393216;
  float* VRIGHT = VLEFT + 393216;
  float* ATTN   = R3;
  float* UPD    = R3 + (size_t)32*NPIX;

  hipMemsetAsync(STATS, 0, (12288 + 16)*sizeof(float), stream);
  prep_kernel<<<2012, 256, 0, stream>>>(c1w, c2w, dw, cf1w, cf2w, wg, wo, wq, WF);
  g_partial_kernel<<<576, 256, 0, stream>>>(td, GC);
  g_final_kernel<<<1, 64, 0, stream>>>(GC, tq, tgw1, tgb1, tgw2, tgb2, G);

  in_proj_kernel<<<9216, 256, 0, stream>>>(feat, in_w, in_b, PX);

#define CONV2_NORM(i) \
  mfma_conv<64,4,1,4,true><<<dim3(6,LDIM), 256, 3*66*272+512, stream>>>( \
      PT, WF + (size_t)(2*(i)+1)*36864, c2b + (i)*64, 64, \
      nullptr, PU, 0, STATS + (2*(i))*1024, STATS + (2*(i)+1)*1024); \
  norm_res_elu_planes<<<4608, 256, 0, stream>>>(PU, PX, STATS + (2*(i)+1)*1024);

#define CONV1(i, DD, WW, GX) \
  mfma_conv<64,4,DD,WW,false><<<dim3(GX,LDIM), (WW)*64, 3*((WW)*16+2*(DD))*272, stream>>>( \
      PX, WF + (size_t)(2*(i))*36864, c1b + (i)*64, 64, \
      nullptr, PT, 0, nullptr, STATS + (2*(i))*1024);

#define ATTN_BLOCK \
  qproj_mfma_kernel<<<1152, 256, 0, stream>>>(PX, WQF, Q); \
  proj_left_kernel<<<384, 256, 0, stream>>>(PX, wl, wvl, LEFTB, VLEFT); \
  proj_right_kernel<<<dim3(12,32), 256, 0, stream>>>(PX, wr, wvr, RIGHTB, VRIGHT); \
  scores_kernel<<<dim3(3,LDIM), 128, 0, stream>>>(Q, LEFTB, RIGHTB, td, G, ATTN); \
  update_kernel<<<dim3(12,LDIM), 256, 0, stream>>>(ATTN, VLEFT, VRIGHT, UPD); \
  gate_mfma_kernel<<<1152, 256, 0, stream>>>(PX, UPD, WGF, WOF, bg);

  CONV1(0, 1, 4, 6)   CONV2_NORM(0)
  CONV1(1, 2, 4, 6)   CONV2_NORM(1)  ATTN_BLOCK
  CONV1(2, 4, 4, 6)   CONV2_NORM(2)
  CONV1(3, 8, 4, 6)   CONV2_NORM(3)  ATTN_BLOCK
  CONV1(4, 16, 2, 12) CONV2_NORM(4)
  CONV1(5, 1, 4, 6)   CONV2_NORM(5)  ATTN_BLOCK

  // distance head: PX -> fp32 logits in R3
  mfma_conv<64,4,1,4,false><<<dim3(6,LDIM), 256, 3*66*272, stream>>>(
      PX, WF + 442368, db, 63, R3, nullptr, 0, nullptr, nullptr);
  sym_kernel<<<dim3(96,LDIM), 256, 0, stream>>>(R3, PT, (float*)d_out);
  // confidence head: PT(64rec) -> PX(32rec, relu) -> R2 fp32 (relu) -> conf
  mfma_conv<64,2,1,4,false><<<dim3(6,LDIM), 256, 3*66*272, stream>>>(
      PT, WF + 479232, cf1b, 32, nullptr, PX, 1, nullptr, nullptr);
  mfma_conv<32,2,1,4,false><<<dim3(6,LDIM), 256, 3*66*144, stream>>>(
      PX, WF + 497664, cf2b, 32, R2, nullptr, 1, nullptr, nullptr);
  conf_kernel<<<18432, 256, 0, stream>>>(R2, cf3w, cf3b, (float*)d_out + (size_t)NPIX*NBINS);
}

// Round 8
// 1731.733 us; speedup vs baseline: 1.3038x; 1.3038x over previous
//
#include <hip/hip_runtime.h>
#include <math.h>

#define LDIM 384
#define NPIX (LDIM*LDIM)
#define NBINS 63

typedef __attribute__((ext_vector_type(8))) __bf16 bf16x8;
typedef __attribute__((ext_vector_type(4))) float floatx4;

__device__ __forceinline__ float sigf(float x){ return 1.f/(1.f+expf(-x)); }

// Prepped weight fragment layout (bf16): [tap][kc][nt][lane(64)][j(8)]
//   B-frag: n = nt*16 + (lane&15), k = kc*32 + (lane>>4)*8 + j
// WF arena offsets (bf16 units):
//   main conv slot s (0..11): s=2i conv1[i], s=2i+1 conv2[i], at s*36864
//   dist: 442368 ; cf1: 479232 ; cf2: 497664 ;
//   wg: 506880 (4096) ; wo: 510976 (2048) ; wq: 513024 (2048) ; total 515072
__global__ __launch_bounds__(256) void prep_kernel(
    const float* __restrict__ c1w, const float* __restrict__ c2w,
    const float* __restrict__ dw, const float* __restrict__ cf1w,
    const float* __restrict__ cf2w, const float* __restrict__ wg,
    const float* __restrict__ wo, const float* __restrict__ wq,
    __bf16* __restrict__ Wf){
  int idx = blockIdx.x*256 + threadIdx.x;
  if (idx >= 515072) return;
  if (idx >= 506880){
    int rel, NT, NDIM; const float* src;
    if (idx < 510976){ rel = idx - 506880; src = wg; NT=4; NDIM=64; }
    else if (idx < 513024){ rel = idx - 510976; src = wo; NT=4; NDIM=64; }
    else { rel = idx - 513024; src = wq; NT=2; NDIM=32; }
    int j = rel & 7, lane = (rel>>3) & 63;
    int r2 = rel >> 9;
    int nt = r2 % NT, kc = r2 / NT;
    int k = kc*32 + (lane>>4)*8 + j;
    int n = nt*16 + (lane&15);
    Wf[idx] = (__bf16)src[(size_t)k*NDIM + n];
    return;
  }
  const float* src; int ICreal, OCreal, ICP, NT, rel;
  if (idx < 442368){
    int layer = idx / 36864; rel = idx - layer*36864;
    int i = layer >> 1;
    src = (layer & 1) ? (c2w + (size_t)i*36864) : (c1w + (size_t)i*36864);
    ICreal=64; OCreal=64; ICP=64; NT=4;
  } else if (idx < 479232){
    rel = idx - 442368; src = dw;   ICreal=64; OCreal=63; ICP=64; NT=4;
  } else if (idx < 497664){
    rel = idx - 479232; src = cf1w; ICreal=63; OCreal=32; ICP=64; NT=2;
  } else {
    rel = idx - 497664; src = cf2w; ICreal=32; OCreal=32; ICP=32; NT=2;
  }
  int j = rel & 7, lane = (rel>>3) & 63;
  int r2 = rel >> 9;
  int nt = r2 % NT; int r3 = r2 / NT;
  int KC = ICP/32;
  int kc = r3 % KC; int tap = r3 / KC;
  int k = kc*32 + (lane>>4)*8 + j;
  int n = nt*16 + (lane&15);
  float v = 0.f;
  if (k < ICreal && n < OCreal) v = src[((size_t)n*ICreal + k)*9 + tap];
  Wf[idx] = (__bf16)v;
}

// ---------- MFMA implicit-GEMM 3x3 dilated conv, compile-time D ----------
template<int ICP, int NT, int D, int WAVES, bool NORM>
__global__ __launch_bounds__(WAVES*64) void mfma_conv(
    const __bf16* __restrict__ Ain, const __bf16* __restrict__ Wf,
    const float* __restrict__ bias, int OC_real,
    float* __restrict__ outF, __bf16* __restrict__ outP,
    int relu, const float* __restrict__ nstats, float* __restrict__ ostats){
  constexpr int KC = ICP/32;
  constexpr int W = WAVES*16;
  constexpr int T = WAVES*64;
  constexpr int SW = W + 2*D;
  constexpr int REC_B = ICP*4;
  constexpr int P_B = REC_B + 16;
  constexpr int PPX = ICP/8;
  constexpr int ROWP = SW*PPX;
  constexpr int TOTP = 3*ROWP;
  constexpr int NCH = (TOTP + T - 1)/T;
  constexpr int OCS = NT*16;
  const int t = threadIdx.x;
  const int wave = t>>6, lane = t&63;
  const int q = lane>>4, col16 = lane&15;
  const int y = blockIdx.y;
  const int x0 = blockIdx.x*W;
  extern __shared__ __align__(16) char smem[];
  char* stage = smem;
  float* muS = (float*)(smem + 3*SW*P_B);

  uint4 vh[NCH], vl[NCH];
  #pragma unroll
  for (int k=0;k<NCH;k++){
    uint4 z = {0u,0u,0u,0u}; vh[k]=z; vl[k]=z;
    int pp = t + k*T;
    if (pp < TOTP){
      int r = pp/ROWP; int rem = pp - r*ROWP;
      int px = rem/PPX; int sub = rem - px*PPX;
      int yr = y + (r-1)*D; int gx = x0 - D + px;
      if ((unsigned)yr < LDIM && (unsigned)gx < LDIM){
        const char* p = (const char*)Ain + ((size_t)yr*LDIM + gx)*REC_B + sub*16;
        vh[k] = *(const uint4*)p;
        vl[k] = *(const uint4*)(p + ICP*2);
      }
    }
  }

  if (NORM){
    if (t < 64){
      float s=0.f, sq=0.f;
      #pragma unroll
      for (int rp=0;rp<8;rp++){ s += nstats[rp*128 + t]; sq += nstats[rp*128 + 64 + t]; }
      float m = s*(1.f/NPIX);
      muS[t] = m;
      muS[64+t] = rsqrtf(sq*(1.f/NPIX) - m*m + 1e-5f);
    }
    __syncthreads();
    #pragma unroll
    for (int k=0;k<NCH;k++){
      int pp = t + k*T;
      if (pp < TOTP){
        int r = pp/ROWP; int rem = pp - r*ROWP;
        int px = rem/PPX; int sub = rem - px*PPX;
        int yr = y + (r-1)*D; int gx = x0 - D + px;
        if ((unsigned)yr < LDIM && (unsigned)gx < LDIM){
          int c0 = sub*8;
          floatx4 mua = *(floatx4*)(muS + c0), mub = *(floatx4*)(muS + c0 + 4);
          floatx4 rsa = *(floatx4*)(muS + 64 + c0), rsb = *(floatx4*)(muS + 64 + c0 + 4);
          __bf16* hp = (__bf16*)&vh[k]; __bf16* lp = (__bf16*)&vl[k];
          #pragma unroll
          for (int j=0;j<8;j++){
            float mu = (j<4) ? mua[j] : mub[j-4];
            float rs = (j<4) ? rsa[j] : rsb[j-4];
            float v = ((float)hp[j] + (float)lp[j] - mu)*rs;
            v = v>0.f ? v : expm1f(v);
            __bf16 h = (__bf16)v; hp[j]=h; lp[j]=(__bf16)(v-(float)h);
          }
        }
      }
    }
  }

  #pragma unroll
  for (int k=0;k<NCH;k++){
    int pp = t + k*T;
    if (pp < TOTP){
      int r = pp/ROWP; int rem = pp - r*ROWP;
      int px = rem/PPX; int sub = rem - px*PPX;
      char* sp = stage + ((size_t)r*SW + px)*P_B + sub*16;
      *(uint4*)sp = vh[k];
      *(uint4*)(sp + ICP*2) = vl[k];
    }
  }
  __syncthreads();

  floatx4 acc[NT];
  #pragma unroll
  for (int b=0;b<NT;b++){ floatx4 z = {0.f,0.f,0.f,0.f}; acc[b]=z; }

  #pragma unroll
  for (int ky=0; ky<3; ky++){
    const char* slot = stage + (size_t)ky*SW*P_B;
    #pragma unroll
    for (int kx=0; kx<3; kx++){
      #pragma unroll
      for (int kc=0; kc<KC; kc++){
        int cl = wave*16 + col16 + kx*D;
        const char* ap = slot + (size_t)cl*P_B + (kc*4+q)*16;
        bf16x8 ah = *(const bf16x8*)ap;
        bf16x8 al = *(const bf16x8*)(ap + ICP*2);
        const __bf16* wkc = Wf + (size_t)((ky*3+kx)*KC + kc)*NT*512 + lane*8;
        #pragma unroll
        for (int nt=0; nt<NT; nt++){
          bf16x8 bfrag = *(const bf16x8*)(wkc + (size_t)nt*512);
          acc[nt] = __builtin_amdgcn_mfma_f32_16x16x32_bf16(ah, bfrag, acc[nt], 0,0,0);
          acc[nt] = __builtin_amdgcn_mfma_f32_16x16x32_bf16(al, bfrag, acc[nt], 0,0,0);
        }
      }
    }
  }

  float* red = (float*)stage;
  if (ostats) __syncthreads();
  #pragma unroll
  for (int nt=0; nt<NT; nt++){
    int oc = nt*16 + col16;
    float bv = (oc < OC_real) ? bias[oc] : 0.f;
    int pxb = x0 + wave*16 + q*4;
    float s=0.f, sq=0.f;
    #pragma unroll
    for (int r=0; r<4; r++){
      float vv = acc[nt][r] + bv;
      if (relu) vv = fmaxf(vv, 0.f);
      size_t pix = (size_t)y*LDIM + pxb + r;
      if (outF) outF[pix*OCS + oc] = vv;
      if (outP){
        __bf16 h = (__bf16)vv;
        __bf16* rec = outP + pix*(size_t)(OCS*2);
        rec[oc] = h; rec[OCS+oc] = (__bf16)(vv - (float)h);
      }
      s += vv; sq += vv*vv;
    }
    if (ostats){
      s  += __shfl_xor(s, 16);  s  += __shfl_xor(s, 32);
      sq += __shfl_xor(sq, 16); sq += __shfl_xor(sq, 32);
      if (q == 0){
        red[oc*WAVES + wave] = s;
        red[OCS*WAVES + oc*WAVES + wave] = sq;
      }
    }
  }
  if (ostats){
    __syncthreads();
    float* oslot = ostats + ((blockIdx.y & 7) << 7);
    if (t < OCS){
      float s=0.f, sq=0.f;
      #pragma unroll
      for (int w=0; w<WAVES; w++){
        s  += red[t*WAVES + w];
        sq += red[OCS*WAVES + t*WAVES + w];
      }
      atomicAdd(&oslot[t], s);
      atomicAdd(&oslot[64+t], sq);
    }
  }
}

// ---------------- input 1x1 conv: NHWC(41) -> hi/lo records(64) ----------------
__global__ __launch_bounds__(256) void in_proj_kernel(
    const float* __restrict__ feat, const float* __restrict__ w,
    const float* __restrict__ b, __bf16* __restrict__ PX){
  __shared__ float sf[16][41];
  __shared__ float sw[64*41];
  int t = threadIdx.x;
  size_t p0 = (size_t)blockIdx.x*16;
  float wv[11];
  #pragma unroll
  for (int k=0;k<11;k++){ int idx=t+k*256; wv[k] = (idx<2624) ? w[idx] : 0.f; }
  float fv[3];
  #pragma unroll
  for (int k=0;k<3;k++){ int idx=t+k*256; fv[k] = (idx<656) ? feat[p0*41 + idx] : 0.f; }
  #pragma unroll
  for (int k=0;k<11;k++){ int idx=t+k*256; if (idx<2624) sw[idx]=wv[k]; }
  #pragma unroll
  for (int k=0;k<3;k++){
    int idx=t+k*256;
    if (idx<656){ int p = idx/41, k2 = idx - p*41; sf[p][k2]=fv[k]; }
  }
  __syncthreads();
  #pragma unroll
  for (int k=0;k<4;k++){
    int item = t + k*256;
    int c = item&63, p = item>>6;
    float acc = b[c];
    #pragma unroll
    for (int kk=0;kk<41;kk++) acc += sf[p][kk]*sw[c*41+kk];
    __bf16 h = (__bf16)acc;
    __bf16* rec = PX + (p0+p)*128;
    rec[c] = h; rec[64+c] = (__bf16)(acc - (float)h);
  }
}

// norm(conv2raw U, 8-replica stats) + residual(PX) -> ELU -> PX (records)
__global__ __launch_bounds__(256) void norm_res_elu_planes(
    const __bf16* __restrict__ U, __bf16* __restrict__ PX,
    const float* __restrict__ stats){
  size_t idx = (size_t)blockIdx.x*256 + threadIdx.x;
  size_t px = idx>>3; int c0 = (int)(idx&7)*8;
  const __bf16* ur = U + px*128;
  __bf16* xr = PX + px*128;
  uint4 uh = *(const uint4*)(ur + c0);
  uint4 ul = *(const uint4*)(ur + 64 + c0);
  uint4 xh = *(uint4*)(xr + c0);
  uint4 xl = *(uint4*)(xr + 64 + c0);
  __bf16* uhp=(__bf16*)&uh; __bf16* ulp=(__bf16*)&ul;
  __bf16* xhp=(__bf16*)&xh; __bf16* xlp=(__bf16*)&xl;
  float mu[8], rs[8];
  #pragma unroll
  for (int k=0;k<8;k++){
    int c = c0+k;
    float s=0.f, sq=0.f;
    #pragma unroll
    for (int rp=0;rp<8;rp++){ s += stats[rp*128 + c]; sq += stats[rp*128 + 64 + c]; }
    float m = s*(1.f/NPIX);
    mu[k]=m; rs[k]=rsqrtf(sq*(1.f/NPIX) - m*m + 1e-5f);
  }
  #pragma unroll
  for (int k=0;k<8;k++){
    float v = ((float)uhp[k] + (float)ulp[k] - mu[k])*rs[k]
            + ((float)xhp[k] + (float)xlp[k]);
    v = v>0.f ? v : expm1f(v);
    __bf16 h = (__bf16)v; xhp[k]=h; xlp[k]=(__bf16)(v-(float)h);
  }
  *(uint4*)(xr + c0) = xh;
  *(uint4*)(xr + 64 + c0) = xl;
}

// ---------------- attention ----------------
__global__ __launch_bounds__(256) void g_partial_kernel(
    const float* __restrict__ td, float* __restrict__ GC){
  size_t base = (size_t)blockIdx.x*256;
  float cnt = (td[base + threadIdx.x] > 0.f) ? 1.f : 0.f;
  __shared__ float red[256];
  red[threadIdx.x]=cnt; __syncthreads();
  for (int st=128; st; st>>=1){
    if (threadIdx.x<st) red[threadIdx.x]+=red[threadIdx.x+st];
    __syncthreads();
  }
  if (threadIdx.x==0) atomicAdd(GC, red[0]);
}

__global__ void g_final_kernel(
    const float* __restrict__ GC, const float* __restrict__ tq,
    const float* __restrict__ w1, const float* __restrict__ b1,
    const float* __restrict__ w2, const float* __restrict__ b2,
    float* __restrict__ G){
  if (threadIdx.x==0){
    float f0 = GC[0]*(1.f/NPIX), f1 = tq[0], f2 = (float)LDIM/512.f;
    float z = b2[0];
    for (int j=0;j<16;j++){
      float h = f0*w1[j] + f1*w1[16+j] + f2*w1[32+j] + b1[j];
      z += (h>0.f?h:0.f)*w2[j];
    }
    G[0] = sigf(z);
  }
}

// q = X @ wq via MFMA; writes Qb bf16 [i][j][32]
__global__ __launch_bounds__(256) void qproj_mfma_kernel(
    const __bf16* __restrict__ PX, const __bf16* __restrict__ WqF,
    __bf16* __restrict__ Qb){
  const int t=threadIdx.x, wave=t>>6, lane=t&63, q=lane>>4, col16=lane&15;
  const size_t p0=(size_t)blockIdx.x*128;
  __shared__ __bf16 Xhi[128*72];
  __shared__ __bf16 Xlo[128*72];
  uint4 sv[8];
  #pragma unroll
  for (int k=0;k<8;k++){
    int c=t+k*256;
    sv[k] = *(const uint4*)((const char*)PX + (p0 + (c>>4))*256 + (c&15)*16);
  }
  #pragma unroll
  for (int k=0;k<8;k++){
    int c=t+k*256; int px=c>>4, sub=c&15;
    *(uint4*)(((sub<8)?Xhi:Xlo) + px*72 + (sub&7)*8) = sv[k];
  }
  __syncthreads();
  floatx4 acc[2][2];
  #pragma unroll
  for (int a=0;a<2;a++)
    #pragma unroll
    for (int b=0;b<2;b++){ floatx4 z={0.f,0.f,0.f,0.f}; acc[a][b]=z; }
  #pragma unroll
  for (int kc=0;kc<2;kc++){
    bf16x8 ah[2], al[2];
    #pragma unroll
    for (int mt=0;mt<2;mt++){
      int row = wave*32 + mt*16 + col16;
      ah[mt] = *(const bf16x8*)(Xhi + row*72 + kc*32 + q*8);
      al[mt] = *(const bf16x8*)(Xlo + row*72 + kc*32 + q*8);
    }
    #pragma unroll
    for (int nt=0;nt<2;nt++){
      bf16x8 b = *(const bf16x8*)(WqF + (kc*2+nt)*512 + lane*8);
      acc[0][nt] = __builtin_amdgcn_mfma_f32_16x16x32_bf16(ah[0], b, acc[0][nt], 0,0,0);
      acc[1][nt] = __builtin_amdgcn_mfma_f32_16x16x32_bf16(ah[1], b, acc[1][nt], 0,0,0);
      acc[0][nt] = __builtin_amdgcn_mfma_f32_16x16x32_bf16(al[0], b, acc[0][nt], 0,0,0);
      acc[1][nt] = __builtin_amdgcn_mfma_f32_16x16x32_bf16(al[1], b, acc[1][nt], 0,0,0);
    }
  }
  #pragma unroll
  for (int mt=0;mt<2;mt++){
    size_t pxb = p0 + wave*32 + mt*16 + q*4;
    #pragma unroll
    for (int nt=0;nt<2;nt++){
      int oc = nt*16 + col16;
      #pragma unroll
      for (int r=0;r<4;r++)
        Qb[(pxb+r)*32 + oc] = (__bf16)acc[mt][nt][r];
    }
  }
}

// leftb bf16 [i][a][n]; vleftTb bf16 [i][n][a]
__global__ __launch_bounds__(256) void proj_left_kernel(
    const __bf16* __restrict__ PX, const float* __restrict__ wl, const float* __restrict__ wvl,
    __bf16* __restrict__ leftb, __bf16* __restrict__ vleftTb){
  int i = blockIdx.x;
  __shared__ float xa[32][65];
  __shared__ float w1s[2048], w2s[2048];
  int c = threadIdx.x & 63;
  for (int a = threadIdx.x>>6; a<32; a+=4){
    const __bf16* rec = PX + ((size_t)i*LDIM + 12*a)*128;
    xa[a][c] = (float)rec[c] + (float)rec[64+c];
  }
  for (int idx=threadIdx.x; idx<2048; idx+=256){ w1s[idx]=wl[idx]; w2s[idx]=wvl[idx]; }
  __syncthreads();
  #pragma unroll
  for (int k=0;k<4;k++){
    int idx = threadIdx.x + k*256;
    int a = idx>>5, n = idx&31;
    float a1=0.f, a2=0.f;
    #pragma unroll
    for (int cc=0;cc<64;cc++){ float v=xa[a][cc]; a1+=v*w1s[cc*32+n]; a2+=v*w2s[cc*32+n]; }
    leftb  [(size_t)i*1024 + a*32 + n] = (__bf16)a1;
    vleftTb[(size_t)i*1024 + n*32 + a] = (__bf16)a2;
  }
}

// grid (12, 32): j0 = bx*32, a = by ; rightb [j][a][n] ; vrightTb [j][n][a]
__global__ __launch_bounds__(256) void proj_right_kernel(
    const __bf16* __restrict__ PX, const float* __restrict__ wr, const float* __restrict__ wvr,
    __bf16* __restrict__ rightb, __bf16* __restrict__ vrightTb){
  int a = blockIdx.y; int row = 12*a;
  int j0 = blockIdx.x*32;
  __shared__ float xr[32][65];
  __shared__ float w1s[2048], w2s[2048];
  for (int idx=threadIdx.x; idx<2048; idx+=256){ w1s[idx]=wr[idx]; w2s[idx]=wvr[idx]; }
  int c = threadIdx.x & 63;
  for (int jl = threadIdx.x>>6; jl<32; jl+=4){
    const __bf16* rec = PX + ((size_t)row*LDIM + j0 + jl)*128;
    xr[jl][c] = (float)rec[c] + (float)rec[64+c];
  }
  __syncthreads();
  #pragma unroll
  for (int k=0;k<4;k++){
    int idx=threadIdx.x+k*256; int jl=idx>>5, n=idx&31;
    float a1=0.f, a2=0.f;
    #pragma unroll
    for (int cc=0;cc<64;cc++){ float v=xr[jl][cc]; a1+=v*w1s[cc*32+n]; a2+=v*w2s[cc*32+n]; }
    rightb  [(size_t)(j0+jl)*1024 + a*32 + n] = (__bf16)a1;
    vrightTb[(size_t)(j0+jl)*1024 + n*32 + a] = (__bf16)a2;
  }
}

// S1: per-i GEMM  S[i,j,a] = Q[i,j,:] . left[i,a,:]
__global__ __launch_bounds__(256) void attn_s1_kernel(
    const __bf16* __restrict__ Qb, const __bf16* __restrict__ leftb,
    float* __restrict__ S){
  const int t=threadIdx.x, wave=t>>6, lane=t&63, q=lane>>4, col16=lane&15;
  const int i = blockIdx.y, j0 = blockIdx.x*128;
  bf16x8 bfrag[2];
  #pragma unroll
  for (int nt=0;nt<2;nt++)
    bfrag[nt] = *(const bf16x8*)(leftb + (size_t)i*1024 + (nt*16+col16)*32 + q*8);
  bf16x8 ah[2];
  #pragma unroll
  for (int mt=0;mt<2;mt++){
    int row = j0 + wave*32 + mt*16 + col16;
    ah[mt] = *(const bf16x8*)(Qb + ((size_t)i*LDIM + row)*32 + q*8);
  }
  floatx4 acc[2][2];
  #pragma unroll
  for (int a=0;a<2;a++)
    #pragma unroll
    for (int b=0;b<2;b++){ floatx4 z={0.f,0.f,0.f,0.f}; acc[a][b]=z; }
  #pragma unroll
  for (int mt=0;mt<2;mt++)
    #pragma unroll
    for (int nt=0;nt<2;nt++)
      acc[mt][nt] = __builtin_amdgcn_mfma_f32_16x16x32_bf16(ah[mt], bfrag[nt], acc[mt][nt], 0,0,0);
  #pragma unroll
  for (int mt=0;mt<2;mt++){
    int jb = j0 + wave*32 + mt*16 + q*4;
    #pragma unroll
    for (int nt=0;nt<2;nt++){
      int a = nt*16 + col16;
      #pragma unroll
      for (int r=0;r<4;r++)
        S[((size_t)i*LDIM + jb + r)*32 + a] = acc[mt][nt][r];
    }
  }
}

// S2: per-j GEMM  S[i,j,a] += Q[i,j,:] . right[j,a,:]
__global__ __launch_bounds__(256) void attn_s2_kernel(
    const __bf16* __restrict__ Qb, const __bf16* __restrict__ rightb,
    float* __restrict__ S){
  const int t=threadIdx.x, wave=t>>6, lane=t&63, q=lane>>4, col16=lane&15;
  const int j = blockIdx.y, i0 = blockIdx.x*128;
  bf16x8 bfrag[2];
  #pragma unroll
  for (int nt=0;nt<2;nt++)
    bfrag[nt] = *(const bf16x8*)(rightb + (size_t)j*1024 + (nt*16+col16)*32 + q*8);
  bf16x8 ah[2];
  #pragma unroll
  for (int mt=0;mt<2;mt++){
    int row = i0 + wave*32 + mt*16 + col16;
    ah[mt] = *(const bf16x8*)(Qb + ((size_t)row*LDIM + j)*32 + q*8);
  }
  floatx4 acc[2][2];
  #pragma unroll
  for (int a=0;a<2;a++)
    #pragma unroll
    for (int b=0;b<2;b++){ floatx4 z={0.f,0.f,0.f,0.f}; acc[a][b]=z; }
  #pragma unroll
  for (int mt=0;mt<2;mt++)
    #pragma unroll
    for (int nt=0;nt<2;nt++)
      acc[mt][nt] = __builtin_amdgcn_mfma_f32_16x16x32_bf16(ah[mt], bfrag[nt], acc[mt][nt], 0,0,0);
  #pragma unroll
  for (int mt=0;mt<2;mt++){
    int ib = i0 + wave*32 + mt*16 + q*4;
    #pragma unroll
    for (int nt=0;nt<2;nt++){
      int a = nt*16 + col16;
      #pragma unroll
      for (int r=0;r<4;r++){
        size_t idx = ((size_t)(ib+r)*LDIM + j)*32 + a;
        S[idx] += acc[mt][nt][r];
      }
    }
  }
}

// softmax(S/sqrt(32) ... wait: S holds raw dot; apply scale+bias here) -> attnb/attnTb
__global__ __launch_bounds__(128) void attn_soft_kernel(
    const float* __restrict__ S, const float* __restrict__ td,
    const float* __restrict__ gp, __bf16* __restrict__ attnb,
    __bf16* __restrict__ attnTb){
  int i = blockIdx.y;
  int j0 = blockIdx.x*128;
  int t = threadIdx.x;
  int j = j0 + t;
  __shared__ float tl[32];
  __shared__ float trS[32*128];
  {
    #pragma unroll
    for (int v=0; v<8; v++){
      int f = t + v*128;
      int a = f>>5, jl4 = (f&31)*4;
      *(floatx4*)(trS + a*128 + jl4) = *(const floatx4*)(td + (size_t)(12*a)*LDIM + j0 + jl4);
    }
    if (t<32) tl[t] = td[(size_t)i*LDIM + 12*t];
  }
  __syncthreads();
  float g = gp[0];
  float tdij = td[(size_t)i*LDIM+j];
  float s[32];
  const floatx4* sp4 = (const floatx4*)(S + ((size_t)i*LDIM+j)*32);
  #pragma unroll
  for (int v=0;v<8;v++){
    floatx4 sv = sp4[v];
    #pragma unroll
    for (int e=0;e<4;e++) s[v*4+e] = sv[e];
  }
  float m = -1e30f;
  #pragma unroll
  for (int a=0;a<32;a++){
    float acc = s[a]*0.17677669529663687f;
    float bias = -fabsf(tl[a] + trS[a*128 + t] - tdij) * (1.0f/12.0f);
    acc += g*bias;
    s[a]=acc;
    m = fmaxf(m, acc);
  }
  float sum=0.f;
  #pragma unroll
  for (int a=0;a<32;a++){ s[a]=expf(s[a]-m); sum+=s[a]; }
  float inv = 1.f/sum;
  bf16x8 pk[4];
  #pragma unroll
  for (int v=0;v<4;v++){
    #pragma unroll
    for (int e=0;e<8;e++) pk[v][e] = (__bf16)(s[v*8+e]*inv);
  }
  bf16x8* op = (bf16x8*)(attnb + ((size_t)i*LDIM+j)*32);
  bf16x8* opT = (bf16x8*)(attnTb + ((size_t)j*LDIM+i)*32);
  #pragma unroll
  for (int v=0;v<4;v++){ op[v]=pk[v]; opT[v]=pk[v]; }
}

// U1: per-i GEMM  UPD[i,j,c] = attn[i,j,:] . vleftT[i,c,:]
__global__ __launch_bounds__(256) void attn_u1_kernel(
    const __bf16* __restrict__ attnb, const __bf16* __restrict__ vleftTb,
    float* __restrict__ UPD){
  const int t=threadIdx.x, wave=t>>6, lane=t&63, q=lane>>4, col16=lane&15;
  const int i = blockIdx.y, j0 = blockIdx.x*128;
  bf16x8 bfrag[2];
  #pragma unroll
  for (int nt=0;nt<2;nt++)
    bfrag[nt] = *(const bf16x8*)(vleftTb + (size_t)i*1024 + (nt*16+col16)*32 + q*8);
  bf16x8 ah[2];
  #pragma unroll
  for (int mt=0;mt<2;mt++){
    int row = j0 + wave*32 + mt*16 + col16;
    ah[mt] = *(const bf16x8*)(attnb + ((size_t)i*LDIM + row)*32 + q*8);
  }
  floatx4 acc[2][2];
  #pragma unroll
  for (int a=0;a<2;a++)
    #pragma unroll
    for (int b=0;b<2;b++){ floatx4 z={0.f,0.f,0.f,0.f}; acc[a][b]=z; }
  #pragma unroll
  for (int mt=0;mt<2;mt++)
    #pragma unroll
    for (int nt=0;nt<2;nt++)
      acc[mt][nt] = __builtin_amdgcn_mfma_f32_16x16x32_bf16(ah[mt], bfrag[nt], acc[mt][nt], 0,0,0);
  #pragma unroll
  for (int mt=0;mt<2;mt++){
    int jb = j0 + wave*32 + mt*16 + q*4;
    #pragma unroll
    for (int nt=0;nt<2;nt++){
      int c = nt*16 + col16;
      #pragma unroll
      for (int r=0;r<4;r++)
        UPD[((size_t)i*LDIM + jb + r)*32 + c] = acc[mt][nt][r];
    }
  }
}

// U2: per-j GEMM  UPD[i,j,c] += attnT[j,i,:] . vrightT[j,c,:]
__global__ __launch_bounds__(256) void attn_u2_kernel(
    const __bf16* __restrict__ attnTb, const __bf16* __restrict__ vrightTb,
    float* __restrict__ UPD){
  const int t=threadIdx.x, wave=t>>6, lane=t&63, q=lane>>4, col16=lane&15;
  const int j = blockIdx.y, i0 = blockIdx.x*128;
  bf16x8 bfrag[2];
  #pragma unroll
  for (int nt=0;nt<2;nt++)
    bfrag[nt] = *(const bf16x8*)(vrightTb + (size_t)j*1024 + (nt*16+col16)*32 + q*8);
  bf16x8 ah[2];
  #pragma unroll
  for (int mt=0;mt<2;mt++){
    int row = i0 + wave*32 + mt*16 + col16;
    ah[mt] = *(const bf16x8*)(attnTb + ((size_t)j*LDIM + row)*32 + q*8);
  }
  floatx4 acc[2][2];
  #pragma unroll
  for (int a=0;a<2;a++)
    #pragma unroll
    for (int b=0;b<2;b++){ floatx4 z={0.f,0.f,0.f,0.f}; acc[a][b]=z; }
  #pragma unroll
  for (int mt=0;mt<2;mt++)
    #pragma unroll
    for (int nt=0;nt<2;nt++)
      acc[mt][nt] = __builtin_amdgcn_mfma_f32_16x16x32_bf16(ah[mt], bfrag[nt], acc[mt][nt], 0,0,0);
  #pragma unroll
  for (int mt=0;mt<2;mt++){
    int ib = i0 + wave*32 + mt*16 + q*4;
    #pragma unroll
    for (int nt=0;nt<2;nt++){
      int c = nt*16 + col16;
      #pragma unroll
      for (int r=0;r<4;r++){
        size_t idx = ((size_t)(ib+r)*LDIM + j)*32 + c;
        UPD[idx] += acc[mt][nt][r];
      }
    }
  }
}

// PX += sigmoid(X@Wg+bg) * (UPD@Wo), in-place on records, via MFMA
__global__ __launch_bounds__(256) void gate_mfma_kernel(
    __bf16* __restrict__ PX, const float* __restrict__ UPD,
    const __bf16* __restrict__ WgF, const __bf16* __restrict__ WoF,
    const float* __restrict__ bg){
  const int t=threadIdx.x, wave=t>>6, lane=t&63, q=lane>>4, col16=lane&15;
  const size_t p0=(size_t)blockIdx.x*128;
  __shared__ __bf16 Xhi[128*72];
  __shared__ __bf16 Xlo[128*72];
  __shared__ __bf16 Ub[128*40];
  uint4 sv[8];
  #pragma unroll
  for (int k=0;k<8;k++){
    int c=t+k*256;
    sv[k] = *(const uint4*)((const char*)PX + (p0 + (c>>4))*256 + (c&15)*16);
  }
  floatx4 uv[4];
  #pragma unroll
  for (int k=0;k<4;k++){
    int p = (t>>3) + k*32;
    uv[k] = *(const floatx4*)(UPD + (p0+p)*32 + (t&7)*4);
  }
  #pragma unroll
  for (int k=0;k<8;k++){
    int c=t+k*256; int px=c>>4, sub=c&15;
    *(uint4*)(((sub<8)?Xhi:Xlo) + px*72 + (sub&7)*8) = sv[k];
  }
  #pragma unroll
  for (int k=0;k<4;k++){
    int p = (t>>3) + k*32;
    __bf16* pu = Ub + p*40 + (t&7)*4;
    #pragma unroll
    for (int kk=0;kk<4;kk++) pu[kk]=(__bf16)uv[k][kk];
  }
  __syncthreads();
  floatx4 accg[2][4], accu[2][4];
  #pragma unroll
  for (int a=0;a<2;a++)
    #pragma unroll
    for (int b=0;b<4;b++){ floatx4 z={0.f,0.f,0.f,0.f}; accg[a][b]=z; accu[a][b]=z; }
  #pragma unroll
  for (int kc=0;kc<2;kc++){
    bf16x8 ah[2], al[2];
    #pragma unroll
    for (int mt=0;mt<2;mt++){
      int row = wave*32 + mt*16 + col16;
      ah[mt] = *(const bf16x8*)(Xhi + row*72 + kc*32 + q*8);
      al[mt] = *(const bf16x8*)(Xlo + row*72 + kc*32 + q*8);
    }
    #pragma unroll
    for (int nt=0;nt<4;nt++){
      bf16x8 b = *(const bf16x8*)(WgF + (kc*4+nt)*512 + lane*8);
      accg[0][nt] = __builtin_amdgcn_mfma_f32_16x16x32_bf16(ah[0], b, accg[0][nt], 0,0,0);
      accg[1][nt] = __builtin_amdgcn_mfma_f32_16x16x32_bf16(ah[1], b, accg[1][nt], 0,0,0);
      accg[0][nt] = __builtin_amdgcn_mfma_f32_16x16x32_bf16(al[0], b, accg[0][nt], 0,0,0);
      accg[1][nt] = __builtin_amdgcn_mfma_f32_16x16x32_bf16(al[1], b, accg[1][nt], 0,0,0);
    }
  }
  {
    bf16x8 au[2];
    #pragma unroll
    for (int mt=0;mt<2;mt++){
      int row = wave*32 + mt*16 + col16;
      au[mt] = *(const bf16x8*)(Ub + row*40 + q*8);
    }
    #pragma unroll
    for (int nt=0;nt<4;nt++){
      bf16x8 b = *(const bf16x8*)(WoF + nt*512 + lane*8);
      accu[0][nt] = __builtin_amdgcn_mfma_f32_16x16x32_bf16(au[0], b, accu[0][nt], 0,0,0);
      accu[1][nt] = __builtin_amdgcn_mfma_f32_16x16x32_bf16(au[1], b, accu[1][nt], 0,0,0);
    }
  }
  #pragma unroll
  for (int mt=0;mt<2;mt++){
    size_t pxb = p0 + wave*32 + mt*16 + q*4;
    #pragma unroll
    for (int nt=0;nt<4;nt++){
      int oc = nt*16 + col16;
      float bgv = bg[oc];
      #pragma unroll
      for (int r=0;r<4;r++){
        __bf16* rec = PX + (pxb+r)*128;
        float xv = (float)rec[oc] + (float)rec[64+oc];
        float g = sigf(accg[mt][nt][r] + bgv);
        float xn = xv + g*accu[mt][nt][r];
        __bf16 h = (__bf16)xn;
        rec[oc] = h; rec[64+oc] = (__bf16)(xn - (float)h);
      }
    }
  }
}

// ---------------- heads ----------------
__global__ __launch_bounds__(256) void sym_kernel(
    const float* __restrict__ lg, __bf16* __restrict__ PS, float* __restrict__ dout){
  int i = blockIdx.y;
  int j = blockIdx.x*4 + (threadIdx.x>>6);
  int o = threadIdx.x & 63;
  float v = 0.5f*(lg[((size_t)i*LDIM+j)*64+o] + lg[((size_t)j*LDIM+i)*64+o]);
  size_t pix = (size_t)i*LDIM+j;
  __bf16 h = (__bf16)v;
  __bf16* rec = PS + pix*128;
  rec[o] = h; rec[64+o] = (__bf16)(v - (float)h);
  if (o<63) dout[pix*63+o] = v;
}

__global__ __launch_bounds__(256) void conf_kernel(
    const float* __restrict__ c2, const float* __restrict__ w,
    const float* __restrict__ b, float* __restrict__ out){
  int t = threadIdx.x;
  size_t pix = (size_t)blockIdx.x*8 + (t>>5);
  int c = t&31;
  float v = c2[pix*32 + c]*w[c];
  #pragma unroll
  for (int off=16; off; off>>=1) v += __shfl_xor(v, off);
  if (c==0) out[pix] = sigf(v + b[0]);
}

extern "C" void kernel_launch(void* const* d_in, const int* in_sizes, int n_in,
                              void* d_out, int out_size, void* d_ws, size_t ws_size,
                              hipStream_t stream){
  const float* feat = (const float*)d_in[0];
  const float* td   = (const float*)d_in[1];
  const float* tq   = (const float*)d_in[2];
  const float* in_w = (const float*)d_in[3];
  const float* in_b = (const float*)d_in[4];
  const float* c1w  = (const float*)d_in[5];
  const float* c1b  = (const float*)d_in[6];
  const float* c2w  = (const float*)d_in[7];
  const float* c2b  = (const float*)d_in[8];
  const float* wq   = (const float*)d_in[9];
  const float* wl   = (const float*)d_in[10];
  const float* wr   = (const float*)d_in[11];
  const float* wvl  = (const float*)d_in[12];
  const float* wvr  = (const float*)d_in[13];
  const float* wo   = (const float*)d_in[14];
  const float* wg   = (const float*)d_in[15];
  const float* bg   = (const float*)d_in[16];
  const float* tgw1 = (const float*)d_in[17];
  const float* tgb1 = (const float*)d_in[18];
  const float* tgw2 = (const float*)d_in[19];
  const float* tgb2 = (const float*)d_in[20];
  const float* dw   = (const float*)d_in[21];
  const float* db   = (const float*)d_in[22];
  const float* cf1w = (const float*)d_in[23];
  const float* cf1b = (const float*)d_in[24];
  const float* cf2w = (const float*)d_in[25];
  const float* cf2b = (const float*)d_in[26];
  const float* cf3w = (const float*)d_in[27];
  const float* cf3b = (const float*)d_in[28];

  float* ws = (float*)d_ws;
  const size_t BUF = (size_t)64*NPIX;
  float* R1 = ws;
  float* R2 = ws + BUF;
  float* R3 = ws + 2*BUF;
  float* STATS = ws + 3*BUF;             // 12 slots x 8 replicas x 128
  float* G     = STATS + 12288;
  float* GC    = G + 1;
  __bf16* WF   = (__bf16*)(G + 16);
  __bf16* WGF  = WF + 506880;
  __bf16* WOF  = WF + 510976;
  __bf16* WQF  = WF + 513024;

  __bf16* PX = (__bf16*)R1;
  __bf16* PT = (__bf16*)R2;
  __bf16* PU = (__bf16*)R3;
  // attention buffers (R2/R3 free during attention)
  char* R2c = (char*)R2;
  __bf16* Qb       = (__bf16*)R2c;                  // 9,437,184 B
  __bf16* ATTNB    = (__bf16*)(R2c +  9437184);     // 9,437,184 B
  __bf16* ATTNTB   = (__bf16*)(R2c + 18874368);     // 9,437,184 B
  __bf16* LEFTB    = (__bf16*)(R2c + 28311552);     //   786,432 B
  __bf16* RIGHTB   = (__bf16*)(R2c + 29097984);
  __bf16* VLEFTTB  = (__bf16*)(R2c + 29884416);
  __bf16* VRIGHTTB = (__bf16*)(R2c + 30670848);
  float* S   = R3;                                  // 18.9 MB
  float* UPD = R3 + (size_t)32*NPIX;                // 18.9 MB

  hipMemsetAsync(STATS, 0, (12288 + 16)*sizeof(float), stream);
  prep_kernel<<<2012, 256, 0, stream>>>(c1w, c2w, dw, cf1w, cf2w, wg, wo, wq, WF);
  g_partial_kernel<<<576, 256, 0, stream>>>(td, GC);
  g_final_kernel<<<1, 64, 0, stream>>>(GC, tq, tgw1, tgb1, tgw2, tgb2, G);

  in_proj_kernel<<<9216, 256, 0, stream>>>(feat, in_w, in_b, PX);

#define CONV2_NORM(i) \
  mfma_conv<64,4,1,4,true><<<dim3(6,LDIM), 256, 3*66*272+512, stream>>>( \
      PT, WF + (size_t)(2*(i)+1)*36864, c2b + (i)*64, 64, \
      nullptr, PU, 0, STATS + (2*(i))*1024, STATS + (2*(i)+1)*1024); \
  norm_res_elu_planes<<<4608, 256, 0, stream>>>(PU, PX, STATS + (2*(i)+1)*1024);

#define CONV1(i, DD, WW, GX) \
  mfma_conv<64,4,DD,WW,false><<<dim3(GX,LDIM), (WW)*64, 3*((WW)*16+2*(DD))*272, stream>>>( \
      PX, WF + (size_t)(2*(i))*36864, c1b + (i)*64, 64, \
      nullptr, PT, 0, nullptr, STATS + (2*(i))*1024);

#define ATTN_BLOCK \
  qproj_mfma_kernel<<<1152, 256, 0, stream>>>(PX, WQF, Qb); \
  proj_left_kernel<<<384, 256, 0, stream>>>(PX, wl, wvl, LEFTB, VLEFTTB); \
  proj_right_kernel<<<dim3(12,32), 256, 0, stream>>>(PX, wr, wvr, RIGHTB, VRIGHTTB); \
  attn_s1_kernel<<<dim3(3,LDIM), 256, 0, stream>>>(Qb, LEFTB, S); \
  attn_s2_kernel<<<dim3(3,LDIM), 256, 0, stream>>>(Qb, RIGHTB, S); \
  attn_soft_kernel<<<dim3(3,LDIM), 128, 0, stream>>>(S, td, G, ATTNB, ATTNTB); \
  attn_u1_kernel<<<dim3(3,LDIM), 256, 0, stream>>>(ATTNB, VLEFTTB, UPD); \
  attn_u2_kernel<<<dim3(3,LDIM), 256, 0, stream>>>(ATTNTB, VRIGHTTB, UPD); \
  gate_mfma_kernel<<<1152, 256, 0, stream>>>(PX, UPD, WGF, WOF, bg);

  CONV1(0, 1, 4, 6)   CONV2_NORM(0)
  CONV1(1, 2, 4, 6)   CONV2_NORM(1)  ATTN_BLOCK
  CONV1(2, 4, 4, 6)   CONV2_NORM(2)
  CONV1(3, 8, 4, 6)   CONV2_NORM(3)  ATTN_BLOCK
  CONV1(4, 16, 2, 12) CONV2_NORM(4)
  CONV1(5, 1, 4, 6)   CONV2_NORM(5)  ATTN_BLOCK

  // distance head: PX -> fp32 logits in R3
  mfma_conv<64,4,1,4,false><<<dim3(6,LDIM), 256, 3*66*272, stream>>>(
      PX, WF + 442368, db, 63, R3, nullptr, 0, nullptr, nullptr);
  sym_kernel<<<dim3(96,LDIM), 256, 0, stream>>>(R3, PT, (float*)d_out);
  // confidence head: PT(64rec) -> PX(32rec, relu) -> R2... use R1 region carefully:
  // cf1 output records (32ch) go to PX region? PX still needed? No — PX dead after dist head.
  mfma_conv<64,2,1,4,false><<<dim3(6,LDIM), 256, 3*66*272, stream>>>(
      PT, WF + 479232, cf1b, 32, nullptr, PX, 1, nullptr, nullptr);
  mfma_conv<32,2,1,4,false><<<dim3(6,LDIM), 256, 3*66*144, stream>>>(
      PX, WF + 497664, cf2b, 32, R3, nullptr, 1, nullptr, nullptr);
  conf_kernel<<<18432, 256, 0, stream>>>(R3, cf3w, cf3b, (float*)d_out + (size_t)NPIX*NBINS);
}